// Round 9
// baseline (1120.388 us; speedup 1.0000x reference)
//
#include <hip/hip_runtime.h>
#include <math.h>

// Problem constants
#define NN 50000
#define NE 800000

typedef __attribute__((ext_vector_type(8))) short  short8;   // 8 bf16 (4 VGPRs)
typedef __attribute__((ext_vector_type(4))) float  floatx4;  // MFMA acc

// bf16 bits <-> float helpers
__device__ __forceinline__ float bf2f(unsigned short u) {
    union { unsigned int i; float f; } v; v.i = ((unsigned int)u) << 16; return v.f;
}
__device__ __forceinline__ unsigned short f2bf(float f) {
    union { float f; unsigned int i; } v; v.f = f;
    unsigned int i = v.i;
    i += 0x7FFFu + ((i >> 16) & 1u);   // round to nearest even
    return (unsigned short)(i >> 16);
}

__device__ __forceinline__ float loadF(const float* p)          { return *p; }
__device__ __forceinline__ float loadF(const unsigned short* p) { return bf2f(*p); }
__device__ __forceinline__ void storeF(float* p, float v)          { *p = v; }
__device__ __forceinline__ void storeF(unsigned short* p, float v) { *p = f2bf(v); }

__device__ __forceinline__ short8 load8(const unsigned short* p) { return *(const short8*)p; }
__device__ __forceinline__ short8 load8(const float* p) {
    float4 u = *(const float4*)p;
    float4 v = *(const float4*)(p + 4);
    short8 s;
    s[0] = (short)f2bf(u.x); s[1] = (short)f2bf(u.y); s[2] = (short)f2bf(u.z); s[3] = (short)f2bf(u.w);
    s[4] = (short)f2bf(v.x); s[5] = (short)f2bf(v.y); s[6] = (short)f2bf(v.z); s[7] = (short)f2bf(v.w);
    return s;
}

__device__ __forceinline__ float leaky(float v) { return (v > 0.f) ? v : 0.2f * v; }

// nontemporal helpers (read-once streams: hit if resident, never allocate)
__device__ __forceinline__ float ntldf(const float* p) { return __builtin_nontemporal_load(p); }

// ---------------------------------------------------------------------------
// CSR build
// ---------------------------------------------------------------------------
__global__ void deg_kernel(const int* __restrict__ edges, int* __restrict__ deg, int E) {
    int e = blockIdx.x * blockDim.x + threadIdx.x;
    if (e < E) atomicAdd(&deg[edges[2 * e + 1]], 1);
}

__global__ void scan_kernel(const int* __restrict__ deg, int* __restrict__ row_ptr,
                            int* __restrict__ cursor, int n) {
    __shared__ int sums[256];
    int t = threadIdx.x;
    const int C = (n + 255) / 256;
    int lo = t * C, hi = min(lo + C, n);
    if (lo > n) lo = n;
    if (hi < lo) hi = lo;
    int s = 0;
    for (int i = lo; i < hi; ++i) s += deg[i];
    sums[t] = s;
    __syncthreads();
    for (int off = 1; off < 256; off <<= 1) {
        int v = (t >= off) ? sums[t - off] : 0;
        __syncthreads();
        sums[t] += v;
        __syncthreads();
    }
    int run = (t == 0) ? 0 : sums[t - 1];
    for (int i = lo; i < hi; ++i) {
        int d = deg[i];
        row_ptr[i] = run;
        cursor[i]  = run;
        run += d;
    }
    if (t == 255) row_ptr[n] = sums[255];
}

__global__ void scatter_kernel(const int* __restrict__ edges, int* __restrict__ cursor,
                               int* __restrict__ edge_src, int* __restrict__ edge_dst, int E) {
    int e = blockIdx.x * blockDim.x + threadIdx.x;
    if (e < E) {
        int sv = edges[2 * e], d = edges[2 * e + 1];
        int pos = atomicAdd(&cursor[d], 1);
        if (pos >= 0 && pos < E) { edge_src[pos] = sv; edge_dst[pos] = d; }
    }
}

// ---------------------------------------------------------------------------
// Per-edge softmax weight precompute: pw[e*H+h] = exp(leaky(e_s+e_d))
// ---------------------------------------------------------------------------
template <int H>
__global__ __launch_bounds__(256) void pw_kernel(const float* __restrict__ e_s,
                                                 const float* __restrict__ e_d,
                                                 const int* __restrict__ esrc,
                                                 const int* __restrict__ edst,
                                                 float* __restrict__ pw, int E) {
    int e = blockIdx.x * blockDim.x + threadIdx.x;
    if (e >= E) return;
    int s = esrc[e], d = edst[e];
    const float* ps = e_s + (size_t)s * H;
    const float* pd = e_d + (size_t)d * H;
#pragma unroll
    for (int h = 0; h < H; ++h)
        pw[(size_t)e * H + h] = __expf(leaky(ps[h] + pd[h]));
}

// ---------------------------------------------------------------------------
// Weight prep: fp32 W[K][N] -> bf16 BT[Npad][K]
// ---------------------------------------------------------------------------
__global__ void transpose_w(const float* __restrict__ W, unsigned short* __restrict__ BT,
                            int K, int N, int Npad) {
    int idx = blockIdx.x * blockDim.x + threadIdx.x;
    if (idx >= Npad * K) return;
    int n = idx / K, k = idx - n * K;
    float v = (n < N) ? W[(size_t)k * N + n] : 0.f;
    BT[idx] = f2bf(v);
}

// ---------------------------------------------------------------------------
// MFMA bf16 GEMM: C = A @ B, B pre-transposed as BT[Npad][K].
// ---------------------------------------------------------------------------
template <typename TA, typename TC>
__global__ __launch_bounds__(256) void gemm_mfma(const TA* __restrict__ A,
                                                 const unsigned short* __restrict__ BT,
                                                 TC* __restrict__ C,
                                                 int M, int K, int NS, int Ncheck) {
    __shared__ __align__(16) unsigned short As[128][40];
    __shared__ __align__(16) unsigned short Bs[128][40];

    const int t    = threadIdx.x;
    const int wave = t >> 6, lane = t & 63;
    const int wm   = (wave >> 1) * 64, wn = (wave & 1) * 64;
    const int l15  = lane & 15, q = lane >> 4;
    const int row0 = blockIdx.y * 128, col0 = blockIdx.x * 128;

    floatx4 acc[4][4];
#pragma unroll
    for (int i = 0; i < 4; ++i)
#pragma unroll
        for (int j = 0; j < 4; ++j) acc[i][j] = (floatx4){0.f, 0.f, 0.f, 0.f};

    for (int k0 = 0; k0 < K; k0 += 32) {
#pragma unroll
        for (int p = 0; p < 2; ++p) {
            int idx = t + 256 * p;
            int r = idx >> 2, qq = idx & 3;
            int ar = row0 + r; ar = (ar < M) ? ar : (M - 1);
            *(short8*)&As[r][qq * 8] = load8(A + (size_t)ar * K + k0 + qq * 8);
            *(short8*)&Bs[r][qq * 8] = load8(BT + (size_t)(col0 + r) * K + k0 + qq * 8);
        }
        __syncthreads();

        short8 af[4], bfr[4];
#pragma unroll
        for (int mi = 0; mi < 4; ++mi) af[mi]  = *(const short8*)&As[wm + 16 * mi + l15][q * 8];
#pragma unroll
        for (int ni = 0; ni < 4; ++ni) bfr[ni] = *(const short8*)&Bs[wn + 16 * ni + l15][q * 8];
#pragma unroll
        for (int mi = 0; mi < 4; ++mi)
#pragma unroll
            for (int ni = 0; ni < 4; ++ni)
                acc[mi][ni] = __builtin_amdgcn_mfma_f32_16x16x32_bf16(af[mi], bfr[ni], acc[mi][ni], 0, 0, 0);
        __syncthreads();
    }

#pragma unroll
    for (int ni = 0; ni < 4; ++ni) {
        int gc = col0 + wn + 16 * ni + l15;
        if (gc >= Ncheck) continue;
#pragma unroll
        for (int mi = 0; mi < 4; ++mi) {
#pragma unroll
            for (int r = 0; r < 4; ++r) {
                int gr = row0 + wm + 16 * mi + q * 4 + r;
                if (gr < M) storeF(C + (size_t)gr * NS + gc, acc[mi][ni][r]);
            }
        }
    }
}

// ---------------------------------------------------------------------------
// Per-node attention scores. One wave per node.
// ---------------------------------------------------------------------------
template <int H, int U>
__global__ __launch_bounds__(64) void escore_kernel(const unsigned short* __restrict__ hbuf,
                                                    int NSTR,
                                                    const float* __restrict__ a_src,
                                                    const float* __restrict__ a_dst,
                                                    float* __restrict__ e_s,
                                                    float* __restrict__ e_d) {
    const int n = blockIdx.x;
    const int lane = threadIdx.x;
    const unsigned short* hrow = hbuf + (size_t)n * NSTR;
#pragma unroll
    for (int h = 0; h < H; ++h) {
        float ps = 0.f, pd = 0.f;
        for (int u = lane; u < U; u += 64) {
            float hv = bf2f(hrow[h * U + u]);
            ps = fmaf(hv, a_src[h * U + u], ps);
            pd = fmaf(hv, a_dst[h * U + u], pd);
        }
#pragma unroll
        for (int off = 32; off; off >>= 1) {
            ps += __shfl_down(ps, off);
            pd += __shfl_down(pd, off);
        }
        if (lane == 0) {
            e_s[(size_t)n * H + h] = ps;
            e_d[(size_t)n * H + h] = pd;
        }
    }
}

// ---------------------------------------------------------------------------
// Wave-per-node softmax aggregation, D=512 (H=4, U=128).
// pw precomputed per edge; 8-edge software pipeline for deep MLP.
// ---------------------------------------------------------------------------
__global__ __launch_bounds__(256) void agg_w512(const unsigned short* __restrict__ hbuf,
                                                const float* __restrict__ pw,
                                                const int* __restrict__ rowp,
                                                const int* __restrict__ esrc,
                                                const unsigned short* res,
                                                unsigned short* out) {
    const int wave = threadIdx.x >> 6, lane = threadIdx.x & 63;
    const int n = blockIdx.x * 4 + wave;      // grid*4 == NN exactly
    const int h = lane >> 4;
    const int beg = rowp[n], end = rowp[n + 1];

    float den = 0.f;
    float acc[8];
#pragma unroll
    for (int j = 0; j < 8; ++j) acc[j] = 0.f;

    int e = beg;
    for (; e + 8 <= end; e += 8) {
        int s[8];
        float p[8];
        short8 r[8];
#pragma unroll
        for (int k = 0; k < 8; ++k) s[k] = esrc[e + k];
#pragma unroll
        for (int k = 0; k < 8; ++k) p[k] = ntldf(pw + (size_t)(e + k) * 4 + h);
#pragma unroll
        for (int k = 0; k < 8; ++k) r[k] = *(const short8*)(hbuf + (size_t)s[k] * 512 + lane * 8);
#pragma unroll
        for (int k = 0; k < 8; ++k) den += p[k];
#pragma unroll
        for (int j = 0; j < 8; ++j) {
            float a = acc[j];
#pragma unroll
            for (int k = 0; k < 8; ++k) a = fmaf(p[k], bf2f((unsigned short)r[k][j]), a);
            acc[j] = a;
        }
    }
    for (; e < end; ++e) {
        int s0 = esrc[e];
        float p0 = ntldf(pw + (size_t)e * 4 + h);
        short8 r0 = *(const short8*)(hbuf + (size_t)s0 * 512 + lane * 8);
        den += p0;
#pragma unroll
        for (int j = 0; j < 8; ++j) acc[j] = fmaf(p0, bf2f((unsigned short)r0[j]), acc[j]);
    }

    const float inv = 1.f / fmaxf(den, 1e-9f);
    short8 rv = *(const short8*)(res + (size_t)n * 512 + lane * 8);
    short8 ov;
#pragma unroll
    for (int j = 0; j < 8; ++j) {
        float z = acc[j] * inv + bf2f((unsigned short)rv[j]);
        z = (z > 0.f) ? z : (__expf(z) - 1.f);   // elu
        ov[j] = (short)f2bf(z);
    }
    *(short8*)(out + (size_t)n * 512 + lane * 8) = ov;
}

// ---------------------------------------------------------------------------
// Wave-per-node aggregation, layer 3: D=726 (H=6, U=121), hbuf stride 728.
// pw precomputed per edge; 4-edge software pipeline. Lane owns chunks
// f0=lane*8 and f1=512+lane*8 (if f1<728); chunk spans at most 2 heads.
// out = mean_heads(agg) + res (fp32, stride 121), NT store (never re-read).
// ---------------------------------------------------------------------------
__global__ __launch_bounds__(256) void agg_w726(const unsigned short* __restrict__ hbuf,
                                                const float* __restrict__ pw,
                                                const int* __restrict__ rowp,
                                                const int* __restrict__ esrc,
                                                const float* res,
                                                float* out) {
    __shared__ float s_vals[4][728];
    const int wave = threadIdx.x >> 6, lane = threadIdx.x & 63;
    const int n = blockIdx.x * 4 + wave;
    const int beg = rowp[n], end = rowp[n + 1];

    // chunk constants
    const int f0 = lane * 8;
    const int hA0 = f0 / 121;
    int cut0 = (hA0 + 1) * 121 - f0; cut0 = (cut0 > 8) ? 8 : cut0;
    const int hB0 = (cut0 < 8) ? min(hA0 + 1, 5) : hA0;
    const int f1 = 512 + lane * 8;
    const bool has1 = (f1 < 728);
    const int hA1 = min(f1 / 121, 5);
    int cut1 = (hA1 + 1) * 121 - f1; cut1 = (cut1 > 8) ? 8 : (cut1 < 0 ? 0 : cut1);
    const int hB1 = (cut1 < 8) ? min(hA1 + 1, 5) : hA1;

    float dA0 = 0.f, dB0 = 0.f, dA1 = 0.f, dB1 = 0.f;
    float acc0[8], acc1[8];
#pragma unroll
    for (int j = 0; j < 8; ++j) { acc0[j] = 0.f; acc1[j] = 0.f; }

    int e = beg;
    for (; e + 4 <= end; e += 4) {
        int s[4];
#pragma unroll
        for (int k = 0; k < 4; ++k) s[k] = esrc[e + k];
        float pA[4], pB[4];
#pragma unroll
        for (int k = 0; k < 4; ++k) {
            const float* q = pw + (size_t)(e + k) * 6;
            pA[k] = ntldf(q + hA0);
            pB[k] = ntldf(q + hB0);
        }
        short8 r0[4];
#pragma unroll
        for (int k = 0; k < 4; ++k) r0[k] = *(const short8*)(hbuf + (size_t)s[k] * 728 + f0);
#pragma unroll
        for (int k = 0; k < 4; ++k) { dA0 += pA[k]; dB0 += pB[k]; }
#pragma unroll
        for (int j = 0; j < 8; ++j) {
            float a = acc0[j];
#pragma unroll
            for (int k = 0; k < 4; ++k)
                a = fmaf((j < cut0) ? pA[k] : pB[k], bf2f((unsigned short)r0[k][j]), a);
            acc0[j] = a;
        }
        if (has1) {
            float qA[4], qB[4];
#pragma unroll
            for (int k = 0; k < 4; ++k) {
                const float* q = pw + (size_t)(e + k) * 6;
                qA[k] = ntldf(q + hA1);
                qB[k] = ntldf(q + hB1);
            }
            short8 r1[4];
#pragma unroll
            for (int k = 0; k < 4; ++k) r1[k] = *(const short8*)(hbuf + (size_t)s[k] * 728 + f1);
#pragma unroll
            for (int k = 0; k < 4; ++k) { dA1 += qA[k]; dB1 += qB[k]; }
#pragma unroll
            for (int j = 0; j < 8; ++j) {
                float a = acc1[j];
#pragma unroll
                for (int k = 0; k < 4; ++k)
                    a = fmaf((j < cut1) ? qA[k] : qB[k], bf2f((unsigned short)r1[k][j]), a);
                acc1[j] = a;
            }
        }
    }
    for (; e < end; ++e) {
        int s = esrc[e];
        const float* q0 = pw + (size_t)e * 6;
        float pA0 = ntldf(q0 + hA0), pB0 = ntldf(q0 + hB0);
        short8 r0 = *(const short8*)(hbuf + (size_t)s * 728 + f0);
        dA0 += pA0; dB0 += pB0;
#pragma unroll
        for (int j = 0; j < 8; ++j)
            acc0[j] = fmaf((j < cut0) ? pA0 : pB0, bf2f((unsigned short)r0[j]), acc0[j]);
        if (has1) {
            float pA1 = ntldf(q0 + hA1), pB1 = ntldf(q0 + hB1);
            short8 r1 = *(const short8*)(hbuf + (size_t)s * 728 + f1);
            dA1 += pA1; dB1 += pB1;
#pragma unroll
            for (int j = 0; j < 8; ++j)
                acc1[j] = fmaf((j < cut1) ? pA1 : pB1, bf2f((unsigned short)r1[j]), acc1[j]);
        }
    }

    const float iA0 = 1.f / fmaxf(dA0, 1e-9f), iB0 = 1.f / fmaxf(dB0, 1e-9f);
    const float iA1 = 1.f / fmaxf(dA1, 1e-9f), iB1 = 1.f / fmaxf(dB1, 1e-9f);
#pragma unroll
    for (int j = 0; j < 8; ++j) s_vals[wave][f0 + j] = acc0[j] * ((j < cut0) ? iA0 : iB0);
    if (has1) {
#pragma unroll
        for (int j = 0; j < 8; ++j) s_vals[wave][f1 + j] = acc1[j] * ((j < cut1) ? iA1 : iB1);
    }
    __syncthreads();

    // mean over 6 heads + residual (fp32 out; res aliases out, own row only)
    for (int u = lane; u < 121; u += 64) {
        float sum = 0.f;
#pragma unroll
        for (int hh = 0; hh < 6; ++hh) sum += s_vals[wave][hh * 121 + u];
        float v = sum * (1.f / 6.f) + res[(size_t)n * 121 + u];
        __builtin_nontemporal_store(v, out + (size_t)n * 121 + u);
    }
}

// ---------------------------------------------------------------------------
// Launch
// ---------------------------------------------------------------------------
static inline size_t align256(size_t x) { return (x + 255) & ~(size_t)255; }

extern "C" void kernel_launch(void* const* d_in, const int* in_sizes, int n_in,
                              void* d_out, int out_size, void* d_ws, size_t ws_size,
                              hipStream_t stream) {
    const float* x0  = (const float*)d_in[0];   // [50000,128] fp32
    const int* edges = (const int*)d_in[1];     // [800000,2] int32
    const float* W1  = (const float*)d_in[2];   // [128,512]
    const float* a1s = (const float*)d_in[3];
    const float* a1d = (const float*)d_in[4];
    const float* R1  = (const float*)d_in[5];   // [128,512]
    const float* W2  = (const float*)d_in[6];   // [512,512]
    const float* a2s = (const float*)d_in[7];
    const float* a2d = (const float*)d_in[8];
    const float* W3  = (const float*)d_in[9];   // [512,726]
    const float* a3s = (const float*)d_in[10];
    const float* a3d = (const float*)d_in[11];
    const float* R3  = (const float*)d_in[12];  // [512,121]
    float* out = (float*)d_out;                 // [50000,121] fp32

    // workspace carve (~155 MB)
    char* w = (char*)d_ws;
    size_t off = 0;
    unsigned short* hbuf = (unsigned short*)(w + off); off = align256(off + (size_t)NN * 728 * 2);
    unsigned short* x1   = (unsigned short*)(w + off); off = align256(off + (size_t)NN * 512 * 2);
    float* es  = (float*)(w + off); off = align256(off + (size_t)NN * 6 * 4);
    float* ed  = (float*)(w + off); off = align256(off + (size_t)NN * 6 * 4);
    int* rowp  = (int*)(w + off);   off = align256(off + (size_t)(NN + 1) * 4);
    int* esrc  = (int*)(w + off);   off = align256(off + (size_t)NE * 4);
    int* edst  = (int*)(w + off);   off = align256(off + (size_t)NE * 4);
    float* pw  = (float*)(w + off); off = align256(off + (size_t)NE * 6 * 4 + 256);
    unsigned short* w1t = (unsigned short*)(w + off); off = align256(off + (size_t)512 * 128 * 2);
    unsigned short* r1t = (unsigned short*)(w + off); off = align256(off + (size_t)512 * 128 * 2);
    unsigned short* w2t = (unsigned short*)(w + off); off = align256(off + (size_t)512 * 512 * 2);
    unsigned short* w3t = (unsigned short*)(w + off); off = align256(off + (size_t)768 * 512 * 2);
    unsigned short* r3t = (unsigned short*)(w + off); off = align256(off + (size_t)128 * 512 * 2);
    int* deg = (int*)es;   // overlay: dead after CSR build
    int* cur = (int*)ed;
    (void)ws_size;

    const int EB = (NE + 255) / 256;
    const int MB = (NN + 127) / 128;   // 391
    const int AB = NN / 4;             // 12500 blocks, 4 waves each

    // --- CSR build ---
    hipMemsetAsync(deg, 0, (size_t)NN * 4, stream);
    deg_kernel<<<EB, 256, 0, stream>>>(edges, deg, NE);
    scan_kernel<<<1, 256, 0, stream>>>(deg, rowp, cur, NN);
    scatter_kernel<<<EB, 256, 0, stream>>>(edges, cur, esrc, edst, NE);

    // --- weight prep ---
    transpose_w<<<(512 * 128 + 255) / 256, 256, 0, stream>>>(W1, w1t, 128, 512, 512);
    transpose_w<<<(512 * 128 + 255) / 256, 256, 0, stream>>>(R1, r1t, 128, 512, 512);
    transpose_w<<<(512 * 512 + 255) / 256, 256, 0, stream>>>(W2, w2t, 512, 512, 512);
    transpose_w<<<(768 * 512 + 255) / 256, 256, 0, stream>>>(W3, w3t, 512, 726, 768);
    transpose_w<<<(128 * 512 + 255) / 256, 256, 0, stream>>>(R3, r3t, 512, 121, 128);

    // --- Layer 1: 128 -> 4x128 concat, res = x0 @ R1, elu ---
    gemm_mfma<<<dim3(4, MB), 256, 0, stream>>>(x0, w1t, hbuf, NN, 128, 512, 512);
    gemm_mfma<<<dim3(4, MB), 256, 0, stream>>>(x0, r1t, x1,   NN, 128, 512, 512);
    escore_kernel<4, 128><<<NN, 64, 0, stream>>>(hbuf, 512, a1s, a1d, es, ed);
    pw_kernel<4><<<EB, 256, 0, stream>>>(es, ed, esrc, edst, pw, NE);
    agg_w512<<<AB, 256, 0, stream>>>(hbuf, pw, rowp, esrc, x1, x1);

    // --- Layer 2: 512 -> 4x128 concat, res = identity(x1), elu (in place) ---
    gemm_mfma<<<dim3(4, MB), 256, 0, stream>>>(x1, w2t, hbuf, NN, 512, 512, 512);
    escore_kernel<4, 128><<<NN, 64, 0, stream>>>(hbuf, 512, a2s, a2d, es, ed);
    pw_kernel<4><<<EB, 256, 0, stream>>>(es, ed, esrc, edst, pw, NE);
    agg_w512<<<AB, 256, 0, stream>>>(hbuf, pw, rowp, esrc, x1, x1);

    // --- Layer 3: 512 -> 6x121 avg, res = x1 @ R3 (fp32 -> d_out), identity ---
    gemm_mfma<<<dim3(6, MB), 256, 0, stream>>>(x1, w3t, hbuf, NN, 512, 728, 726);
    gemm_mfma<<<dim3(1, MB), 256, 0, stream>>>(x1, r3t, out,  NN, 512, 121, 121);
    escore_kernel<6, 121><<<NN, 64, 0, stream>>>(hbuf, 728, a3s, a3d, es, ed);
    pw_kernel<6><<<EB, 256, 0, stream>>>(es, ed, esrc, edst, pw, NE);
    agg_w726<<<AB, 256, 0, stream>>>(hbuf, pw, rowp, esrc, out, out);
}

// Round 10
// 1087.759 us; speedup vs baseline: 1.0300x; 1.0300x over previous
//
#include <hip/hip_runtime.h>
#include <math.h>

// Problem constants
#define NN 50000
#define NE 800000

typedef __attribute__((ext_vector_type(8))) short  short8;   // 8 bf16 (4 VGPRs)
typedef __attribute__((ext_vector_type(4))) float  floatx4;  // MFMA acc

// bf16 bits <-> float helpers
__device__ __forceinline__ float bf2f(unsigned short u) {
    union { unsigned int i; float f; } v; v.i = ((unsigned int)u) << 16; return v.f;
}
__device__ __forceinline__ unsigned short f2bf(float f) {
    union { float f; unsigned int i; } v; v.f = f;
    unsigned int i = v.i;
    i += 0x7FFFu + ((i >> 16) & 1u);   // round to nearest even
    return (unsigned short)(i >> 16);
}

__device__ __forceinline__ void storeF(float* p, float v)          { *p = v; }
__device__ __forceinline__ void storeF(unsigned short* p, float v) { *p = f2bf(v); }

__device__ __forceinline__ float leaky(float v) { return (v > 0.f) ? v : 0.2f * v; }
__device__ __forceinline__ float ntldf(const float* p) { return __builtin_nontemporal_load(p); }

// async 16B global -> LDS (gfx950 global_load_lds_dwordx4)
__device__ __forceinline__ void gload_lds16(const unsigned short* g, unsigned short* l) {
    __builtin_amdgcn_global_load_lds(
        (const __attribute__((address_space(1))) unsigned int*)g,
        (__attribute__((address_space(3))) unsigned int*)l, 16, 0, 0);
}

// ---------------------------------------------------------------------------
// CSR build
// ---------------------------------------------------------------------------
__global__ void deg_kernel(const int* __restrict__ edges, int* __restrict__ deg, int E) {
    int e = blockIdx.x * blockDim.x + threadIdx.x;
    if (e < E) atomicAdd(&deg[edges[2 * e + 1]], 1);
}

__global__ void scan_kernel(const int* __restrict__ deg, int* __restrict__ row_ptr,
                            int* __restrict__ cursor, int n) {
    __shared__ int sums[256];
    int t = threadIdx.x;
    const int C = (n + 255) / 256;
    int lo = t * C, hi = min(lo + C, n);
    if (lo > n) lo = n;
    if (hi < lo) hi = lo;
    int s = 0;
    for (int i = lo; i < hi; ++i) s += deg[i];
    sums[t] = s;
    __syncthreads();
    for (int off = 1; off < 256; off <<= 1) {
        int v = (t >= off) ? sums[t - off] : 0;
        __syncthreads();
        sums[t] += v;
        __syncthreads();
    }
    int run = (t == 0) ? 0 : sums[t - 1];
    for (int i = lo; i < hi; ++i) {
        int d = deg[i];
        row_ptr[i] = run;
        cursor[i]  = run;
        run += d;
    }
    if (t == 255) row_ptr[n] = sums[255];
}

__global__ void scatter_kernel(const int* __restrict__ edges, int* __restrict__ cursor,
                               int* __restrict__ edge_src, int* __restrict__ edge_dst, int E) {
    int e = blockIdx.x * blockDim.x + threadIdx.x;
    if (e < E) {
        int sv = edges[2 * e], d = edges[2 * e + 1];
        int pos = atomicAdd(&cursor[d], 1);
        if (pos >= 0 && pos < E) { edge_src[pos] = sv; edge_dst[pos] = d; }
    }
}

// ---------------------------------------------------------------------------
// Per-edge softmax weight precompute: pw[e*H+h] = exp(leaky(e_s+e_d))
// ---------------------------------------------------------------------------
template <int H>
__global__ __launch_bounds__(256) void pw_kernel(const float* __restrict__ e_s,
                                                 const float* __restrict__ e_d,
                                                 const int* __restrict__ esrc,
                                                 const int* __restrict__ edst,
                                                 float* __restrict__ pw, int E) {
    int e = blockIdx.x * blockDim.x + threadIdx.x;
    if (e >= E) return;
    int s = esrc[e], d = edst[e];
    const float* ps = e_s + (size_t)s * H;
    const float* pd = e_d + (size_t)d * H;
#pragma unroll
    for (int h = 0; h < H; ++h)
        pw[(size_t)e * H + h] = __expf(leaky(ps[h] + pd[h]));
}

// ---------------------------------------------------------------------------
// Weight prep: fp32 W[K][N] -> bf16 BT[Npad][K];  x0 fp32 -> bf16
// ---------------------------------------------------------------------------
__global__ void transpose_w(const float* __restrict__ W, unsigned short* __restrict__ BT,
                            int K, int N, int Npad) {
    int idx = blockIdx.x * blockDim.x + threadIdx.x;
    if (idx >= Npad * K) return;
    int n = idx / K, k = idx - n * K;
    float v = (n < N) ? W[(size_t)k * N + n] : 0.f;
    BT[idx] = f2bf(v);
}

__global__ __launch_bounds__(256) void f32_to_bf16(const float* __restrict__ in,
                                                   unsigned short* __restrict__ out, int n4) {
    int i = (blockIdx.x * blockDim.x + threadIdx.x) * 4;
    if (i + 3 < n4) {
        float4 v = *(const float4*)(in + i);
        ushort4 o;
        o.x = f2bf(v.x); o.y = f2bf(v.y); o.z = f2bf(v.z); o.w = f2bf(v.w);
        *(ushort4*)(out + i) = o;
    }
}

// ---------------------------------------------------------------------------
// MFMA bf16 GEMM with async global->LDS staging (m97 recipe).
// C = A @ B, B pre-transposed as BT[Npad][K]. A bf16, row stride K.
// 128x128 block tile, 4 waves (2x2), each 64x64 via 4x4 of 16x16x32 MFMA.
// LDS tiles UNPADDED 128x32 (64 B row stride) — required by global_load_lds
// (wave-uniform base + lane*16 contiguous). K % 32 == 0.
// ---------------------------------------------------------------------------
template <typename TC>
__global__ __launch_bounds__(256) void gemm_mfma(const unsigned short* __restrict__ A,
                                                 const unsigned short* __restrict__ BT,
                                                 TC* __restrict__ C,
                                                 int M, int K, int NS, int Ncheck) {
    __shared__ __align__(16) unsigned short As[128 * 32];
    __shared__ __align__(16) unsigned short Bs[128 * 32];

    const int t    = threadIdx.x;
    const int wave = t >> 6, lane = t & 63;
    const int wm   = (wave >> 1) * 64, wn = (wave & 1) * 64;
    const int l15  = lane & 15, q = lane >> 4;
    const int row0 = blockIdx.y * 128, col0 = blockIdx.x * 128;

    floatx4 acc[4][4];
#pragma unroll
    for (int i = 0; i < 4; ++i)
#pragma unroll
        for (int j = 0; j < 4; ++j) acc[i][j] = (floatx4){0.f, 0.f, 0.f, 0.f};

    for (int k0 = 0; k0 < K; k0 += 32) {
        // async stage 128x32 A and B tiles: thread idx -> LDS byte offset idx*16
#pragma unroll
        for (int p = 0; p < 2; ++p) {
            int idx = p * 256 + t;
            int r = idx >> 2, qq = idx & 3;
            int ar = row0 + r; ar = (ar < M) ? ar : (M - 1);   // clamp (never stored)
            unsigned short* ldsA = As + (p * 2048 + wave * 512);   // bytes/2
            unsigned short* ldsB = Bs + (p * 2048 + wave * 512);
            gload_lds16(A  + (size_t)ar * K + k0 + qq * 8, ldsA);
            gload_lds16(BT + (size_t)(col0 + r) * K + k0 + qq * 8, ldsB);
        }
        __syncthreads();

        short8 af[4], bfr[4];
#pragma unroll
        for (int mi = 0; mi < 4; ++mi) af[mi]  = *(const short8*)&As[(wm + 16 * mi + l15) * 32 + q * 8];
#pragma unroll
        for (int ni = 0; ni < 4; ++ni) bfr[ni] = *(const short8*)&Bs[(wn + 16 * ni + l15) * 32 + q * 8];
#pragma unroll
        for (int mi = 0; mi < 4; ++mi)
#pragma unroll
            for (int ni = 0; ni < 4; ++ni)
                acc[mi][ni] = __builtin_amdgcn_mfma_f32_16x16x32_bf16(af[mi], bfr[ni], acc[mi][ni], 0, 0, 0);
        __syncthreads();
    }

#pragma unroll
    for (int ni = 0; ni < 4; ++ni) {
        int gc = col0 + wn + 16 * ni + l15;
        if (gc >= Ncheck) continue;
#pragma unroll
        for (int mi = 0; mi < 4; ++mi) {
#pragma unroll
            for (int r = 0; r < 4; ++r) {
                int gr = row0 + wm + 16 * mi + q * 4 + r;
                if (gr < M) storeF(C + (size_t)gr * NS + gc, acc[mi][ni][r]);
            }
        }
    }
}

// ---------------------------------------------------------------------------
// escore, H=4 U=128 (D=512, hbuf stride 512). 4 nodes/block, one wave each.
// Lane l: head h=l>>4, features (l&15)*8..+8 -> short8 load, 16-lane reduce.
// ---------------------------------------------------------------------------
__global__ __launch_bounds__(256) void escore4(const unsigned short* __restrict__ hbuf,
                                               const float* __restrict__ a_src,
                                               const float* __restrict__ a_dst,
                                               float* __restrict__ e_s,
                                               float* __restrict__ e_d) {
    const int wave = threadIdx.x >> 6, lane = threadIdx.x & 63;
    const int n = blockIdx.x * 4 + wave;
    const int h = lane >> 4, seg = lane & 15;

    short8 hv = *(const short8*)(hbuf + (size_t)n * 512 + lane * 8);
    float4 as0 = *(const float4*)(a_src + lane * 8);
    float4 as1 = *(const float4*)(a_src + lane * 8 + 4);
    float4 ad0 = *(const float4*)(a_dst + lane * 8);
    float4 ad1 = *(const float4*)(a_dst + lane * 8 + 4);
    float av[8] = {as0.x, as0.y, as0.z, as0.w, as1.x, as1.y, as1.z, as1.w};
    float dv[8] = {ad0.x, ad0.y, ad0.z, ad0.w, ad1.x, ad1.y, ad1.z, ad1.w};

    float ps = 0.f, pd = 0.f;
#pragma unroll
    for (int j = 0; j < 8; ++j) {
        float x = bf2f((unsigned short)hv[j]);
        ps = fmaf(x, av[j], ps);
        pd = fmaf(x, dv[j], pd);
    }
#pragma unroll
    for (int off = 1; off < 16; off <<= 1) {
        ps += __shfl_xor(ps, off);
        pd += __shfl_xor(pd, off);
    }
    if (seg == 0) {
        e_s[(size_t)n * 4 + h] = ps;
        e_d[(size_t)n * 4 + h] = pd;
    }
}

// ---------------------------------------------------------------------------
// escore, H=6 U=121 (D=726, hbuf stride 728). 4 nodes/block, one wave each.
// Lane owns chunks f0=lane*8 and f1=512+lane*8 (if <728), head-split at cut;
// segmented reduce via LDS atomics. Guards f >= 726 (padding garbage).
// ---------------------------------------------------------------------------
__global__ __launch_bounds__(256) void escore6(const unsigned short* __restrict__ hbuf,
                                               const float* __restrict__ a_src,
                                               const float* __restrict__ a_dst,
                                               float* __restrict__ e_s,
                                               float* __restrict__ e_d) {
    __shared__ float red[4][6][2];
    const int wave = threadIdx.x >> 6, lane = threadIdx.x & 63;
    const int n = blockIdx.x * 4 + wave;

    if (lane < 12) red[wave][lane >> 1][lane & 1] = 0.f;
    __syncthreads();

    // chunk 0: f0 in [0,512), all features valid
    const int f0 = lane * 8;
    const int hA0 = f0 / 121;
    int cut0 = (hA0 + 1) * 121 - f0; cut0 = (cut0 > 8) ? 8 : cut0;
    const int hB0 = (cut0 < 8) ? (hA0 + 1) : hA0;
    {
        short8 hv = *(const short8*)(hbuf + (size_t)n * 728 + f0);
        float psA = 0.f, pdA = 0.f, psB = 0.f, pdB = 0.f;
#pragma unroll
        for (int j = 0; j < 8; ++j) {
            float x = bf2f((unsigned short)hv[j]);
            float a = a_src[f0 + j], d = a_dst[f0 + j];
            if (j < cut0) { psA = fmaf(x, a, psA); pdA = fmaf(x, d, pdA); }
            else          { psB = fmaf(x, a, psB); pdB = fmaf(x, d, pdB); }
        }
        atomicAdd(&red[wave][hA0][0], psA);
        atomicAdd(&red[wave][hA0][1], pdA);
        if (cut0 < 8) {
            atomicAdd(&red[wave][hB0][0], psB);
            atomicAdd(&red[wave][hB0][1], pdB);
        }
    }
    // chunk 1: f1 in [512,728); guard f >= 726
    const int f1 = 512 + lane * 8;
    if (f1 < 728) {
        const int hA1 = (f1 < 726) ? (f1 / 121) : 5;
        int cut1 = (hA1 + 1) * 121 - f1; cut1 = (cut1 > 8) ? 8 : (cut1 < 0 ? 0 : cut1);
        const int hB1 = (cut1 < 8) ? min(hA1 + 1, 5) : hA1;
        short8 hv = *(const short8*)(hbuf + (size_t)n * 728 + f1);
        float psA = 0.f, pdA = 0.f, psB = 0.f, pdB = 0.f;
#pragma unroll
        for (int j = 0; j < 8; ++j) {
            if (f1 + j >= 726) continue;
            float x = bf2f((unsigned short)hv[j]);
            float a = a_src[f1 + j], d = a_dst[f1 + j];
            if (j < cut1) { psA = fmaf(x, a, psA); pdA = fmaf(x, d, pdA); }
            else          { psB = fmaf(x, a, psB); pdB = fmaf(x, d, pdB); }
        }
        atomicAdd(&red[wave][hA1][0], psA);
        atomicAdd(&red[wave][hA1][1], pdA);
        if (cut1 < 8) {
            atomicAdd(&red[wave][hB1][0], psB);
            atomicAdd(&red[wave][hB1][1], pdB);
        }
    }
    __syncthreads();
    if (lane < 6) {
        e_s[(size_t)n * 6 + lane] = red[wave][lane][0];
        e_d[(size_t)n * 6 + lane] = red[wave][lane][1];
    }
}

// ---------------------------------------------------------------------------
// Wave-per-node softmax aggregation, D=512 (H=4, U=128). 4-edge pipeline.
// ---------------------------------------------------------------------------
__global__ __launch_bounds__(256) void agg_w512(const unsigned short* __restrict__ hbuf,
                                                const float* __restrict__ pw,
                                                const int* __restrict__ rowp,
                                                const int* __restrict__ esrc,
                                                const unsigned short* res,
                                                unsigned short* out) {
    const int wave = threadIdx.x >> 6, lane = threadIdx.x & 63;
    const int n = blockIdx.x * 4 + wave;      // grid*4 == NN exactly
    const int h = lane >> 4;
    const int beg = rowp[n], end = rowp[n + 1];

    float den = 0.f;
    float acc[8];
#pragma unroll
    for (int j = 0; j < 8; ++j) acc[j] = 0.f;

    int e = beg;
    for (; e + 4 <= end; e += 4) {
        int s0 = esrc[e], s1 = esrc[e + 1], s2 = esrc[e + 2], s3 = esrc[e + 3];
        float p0 = ntldf(pw + (size_t)e * 4 + h);
        float p1 = ntldf(pw + (size_t)(e + 1) * 4 + h);
        float p2 = ntldf(pw + (size_t)(e + 2) * 4 + h);
        float p3 = ntldf(pw + (size_t)(e + 3) * 4 + h);
        short8 r0 = *(const short8*)(hbuf + (size_t)s0 * 512 + lane * 8);
        short8 r1 = *(const short8*)(hbuf + (size_t)s1 * 512 + lane * 8);
        short8 r2 = *(const short8*)(hbuf + (size_t)s2 * 512 + lane * 8);
        short8 r3 = *(const short8*)(hbuf + (size_t)s3 * 512 + lane * 8);
        den += (p0 + p1) + (p2 + p3);
#pragma unroll
        for (int j = 0; j < 8; ++j)
            acc[j] = fmaf(p0, bf2f((unsigned short)r0[j]),
                     fmaf(p1, bf2f((unsigned short)r1[j]),
                     fmaf(p2, bf2f((unsigned short)r2[j]),
                     fmaf(p3, bf2f((unsigned short)r3[j]), acc[j]))));
    }
    for (; e < end; ++e) {
        int s0 = esrc[e];
        float p0 = ntldf(pw + (size_t)e * 4 + h);
        short8 r0 = *(const short8*)(hbuf + (size_t)s0 * 512 + lane * 8);
        den += p0;
#pragma unroll
        for (int j = 0; j < 8; ++j) acc[j] = fmaf(p0, bf2f((unsigned short)r0[j]), acc[j]);
    }

    const float inv = 1.f / fmaxf(den, 1e-9f);
    short8 rv = *(const short8*)(res + (size_t)n * 512 + lane * 8);
    short8 ov;
#pragma unroll
    for (int j = 0; j < 8; ++j) {
        float z = acc[j] * inv + bf2f((unsigned short)rv[j]);
        z = (z > 0.f) ? z : (__expf(z) - 1.f);   // elu
        ov[j] = (short)f2bf(z);
    }
    *(short8*)(out + (size_t)n * 512 + lane * 8) = ov;
}

// ---------------------------------------------------------------------------
// Wave-per-node aggregation, layer 3: D=726 (H=6, U=121), hbuf stride 728.
// 4-edge pipeline; NT final store.
// ---------------------------------------------------------------------------
__global__ __launch_bounds__(256) void agg_w726(const unsigned short* __restrict__ hbuf,
                                                const float* __restrict__ pw,
                                                const int* __restrict__ rowp,
                                                const int* __restrict__ esrc,
                                                const float* res,
                                                float* out) {
    __shared__ float s_vals[4][728];
    const int wave = threadIdx.x >> 6, lane = threadIdx.x & 63;
    const int n = blockIdx.x * 4 + wave;
    const int beg = rowp[n], end = rowp[n + 1];

    const int f0 = lane * 8;
    const int hA0 = f0 / 121;
    int cut0 = (hA0 + 1) * 121 - f0; cut0 = (cut0 > 8) ? 8 : cut0;
    const int hB0 = (cut0 < 8) ? min(hA0 + 1, 5) : hA0;
    const int f1 = 512 + lane * 8;
    const bool has1 = (f1 < 728);
    const int hA1 = min(f1 / 121, 5);
    int cut1 = (hA1 + 1) * 121 - f1; cut1 = (cut1 > 8) ? 8 : (cut1 < 0 ? 0 : cut1);
    const int hB1 = (cut1 < 8) ? min(hA1 + 1, 5) : hA1;

    float dA0 = 0.f, dB0 = 0.f, dA1 = 0.f, dB1 = 0.f;
    float acc0[8], acc1[8];
#pragma unroll
    for (int j = 0; j < 8; ++j) { acc0[j] = 0.f; acc1[j] = 0.f; }

    int e = beg;
    for (; e + 4 <= end; e += 4) {
        int s[4];
#pragma unroll
        for (int k = 0; k < 4; ++k) s[k] = esrc[e + k];
        float pA[4], pB[4];
#pragma unroll
        for (int k = 0; k < 4; ++k) {
            const float* q = pw + (size_t)(e + k) * 6;
            pA[k] = ntldf(q + hA0);
            pB[k] = ntldf(q + hB0);
        }
        short8 r0[4];
#pragma unroll
        for (int k = 0; k < 4; ++k) r0[k] = *(const short8*)(hbuf + (size_t)s[k] * 728 + f0);
#pragma unroll
        for (int k = 0; k < 4; ++k) { dA0 += pA[k]; dB0 += pB[k]; }
#pragma unroll
        for (int j = 0; j < 8; ++j) {
            float a = acc0[j];
#pragma unroll
            for (int k = 0; k < 4; ++k)
                a = fmaf((j < cut0) ? pA[k] : pB[k], bf2f((unsigned short)r0[k][j]), a);
            acc0[j] = a;
        }
        if (has1) {
            float qA[4], qB[4];
#pragma unroll
            for (int k = 0; k < 4; ++k) {
                const float* q = pw + (size_t)(e + k) * 6;
                qA[k] = ntldf(q + hA1);
                qB[k] = ntldf(q + hB1);
            }
            short8 r1[4];
#pragma unroll
            for (int k = 0; k < 4; ++k) r1[k] = *(const short8*)(hbuf + (size_t)s[k] * 728 + f1);
#pragma unroll
            for (int k = 0; k < 4; ++k) { dA1 += qA[k]; dB1 += qB[k]; }
#pragma unroll
            for (int j = 0; j < 8; ++j) {
                float a = acc1[j];
#pragma unroll
                for (int k = 0; k < 4; ++k)
                    a = fmaf((j < cut1) ? qA[k] : qB[k], bf2f((unsigned short)r1[k][j]), a);
                acc1[j] = a;
            }
        }
    }
    for (; e < end; ++e) {
        int s = esrc[e];
        const float* q0 = pw + (size_t)e * 6;
        float pA0 = ntldf(q0 + hA0), pB0 = ntldf(q0 + hB0);
        short8 r0 = *(const short8*)(hbuf + (size_t)s * 728 + f0);
        dA0 += pA0; dB0 += pB0;
#pragma unroll
        for (int j = 0; j < 8; ++j)
            acc0[j] = fmaf((j < cut0) ? pA0 : pB0, bf2f((unsigned short)r0[j]), acc0[j]);
        if (has1) {
            float pA1 = ntldf(q0 + hA1), pB1 = ntldf(q0 + hB1);
            short8 r1 = *(const short8*)(hbuf + (size_t)s * 728 + f1);
            dA1 += pA1; dB1 += pB1;
#pragma unroll
            for (int j = 0; j < 8; ++j)
                acc1[j] = fmaf((j < cut1) ? pA1 : pB1, bf2f((unsigned short)r1[j]), acc1[j]);
        }
    }

    const float iA0 = 1.f / fmaxf(dA0, 1e-9f), iB0 = 1.f / fmaxf(dB0, 1e-9f);
    const float iA1 = 1.f / fmaxf(dA1, 1e-9f), iB1 = 1.f / fmaxf(dB1, 1e-9f);
#pragma unroll
    for (int j = 0; j < 8; ++j) s_vals[wave][f0 + j] = acc0[j] * ((j < cut0) ? iA0 : iB0);
    if (has1) {
#pragma unroll
        for (int j = 0; j < 8; ++j) s_vals[wave][f1 + j] = acc1[j] * ((j < cut1) ? iA1 : iB1);
    }
    __syncthreads();

    for (int u = lane; u < 121; u += 64) {
        float sum = 0.f;
#pragma unroll
        for (int hh = 0; hh < 6; ++hh) sum += s_vals[wave][hh * 121 + u];
        float v = sum * (1.f / 6.f) + res[(size_t)n * 121 + u];
        __builtin_nontemporal_store(v, out + (size_t)n * 121 + u);
    }
}

// ---------------------------------------------------------------------------
// Launch
// ---------------------------------------------------------------------------
static inline size_t align256(size_t x) { return (x + 255) & ~(size_t)255; }

extern "C" void kernel_launch(void* const* d_in, const int* in_sizes, int n_in,
                              void* d_out, int out_size, void* d_ws, size_t ws_size,
                              hipStream_t stream) {
    const float* x0  = (const float*)d_in[0];   // [50000,128] fp32
    const int* edges = (const int*)d_in[1];     // [800000,2] int32
    const float* W1  = (const float*)d_in[2];   // [128,512]
    const float* a1s = (const float*)d_in[3];
    const float* a1d = (const float*)d_in[4];
    const float* R1  = (const float*)d_in[5];   // [128,512]
    const float* W2  = (const float*)d_in[6];   // [512,512]
    const float* a2s = (const float*)d_in[7];
    const float* a2d = (const float*)d_in[8];
    const float* W3  = (const float*)d_in[9];   // [512,726]
    const float* a3s = (const float*)d_in[10];
    const float* a3d = (const float*)d_in[11];
    const float* R3  = (const float*)d_in[12];  // [512,121]
    float* out = (float*)d_out;                 // [50000,121] fp32

    // workspace carve (~155 MB; proven safe rounds 8-9)
    char* w = (char*)d_ws;
    size_t off = 0;
    unsigned short* hbuf = (unsigned short*)(w + off); off = align256(off + (size_t)NN * 728 * 2);
    unsigned short* x1   = (unsigned short*)(w + off); off = align256(off + (size_t)NN * 512 * 2);
    float* es  = (float*)(w + off); off = align256(off + (size_t)NN * 6 * 4);
    float* ed  = (float*)(w + off); off = align256(off + (size_t)NN * 6 * 4);
    int* rowp  = (int*)(w + off);   off = align256(off + (size_t)(NN + 1) * 4);
    int* esrc  = (int*)(w + off);   off = align256(off + (size_t)NE * 4);
    int* edst  = (int*)(w + off);   off = align256(off + (size_t)NE * 4);
    float* pw  = (float*)(w + off); off = align256(off + (size_t)NE * 6 * 4 + 256);
    unsigned short* w1t = (unsigned short*)(w + off); off = align256(off + (size_t)512 * 128 * 2);
    unsigned short* r1t = (unsigned short*)(w + off); off = align256(off + (size_t)512 * 128 * 2);
    unsigned short* w2t = (unsigned short*)(w + off); off = align256(off + (size_t)512 * 512 * 2);
    unsigned short* w3t = (unsigned short*)(w + off); off = align256(off + (size_t)768 * 512 * 2);
    unsigned short* r3t = (unsigned short*)(w + off); off = align256(off + (size_t)128 * 512 * 2);
    int* deg = (int*)es;                     // overlay: dead after CSR build
    int* cur = (int*)ed;
    unsigned short* x0b = (unsigned short*)pw;   // overlay: x0 bf16, dead before pw written
    (void)ws_size;

    const int EB = (NE + 255) / 256;
    const int MB = (NN + 127) / 128;   // 391
    const int AB = NN / 4;             // 12500 blocks, 4 waves each

    // --- CSR build ---
    hipMemsetAsync(deg, 0, (size_t)NN * 4, stream);
    deg_kernel<<<EB, 256, 0, stream>>>(edges, deg, NE);
    scan_kernel<<<1, 256, 0, stream>>>(deg, rowp, cur, NN);
    scatter_kernel<<<EB, 256, 0, stream>>>(edges, cur, esrc, edst, NE);

    // --- weight prep + x0 bf16 ---
    transpose_w<<<(512 * 128 + 255) / 256, 256, 0, stream>>>(W1, w1t, 128, 512, 512);
    transpose_w<<<(512 * 128 + 255) / 256, 256, 0, stream>>>(R1, r1t, 128, 512, 512);
    transpose_w<<<(512 * 512 + 255) / 256, 256, 0, stream>>>(W2, w2t, 512, 512, 512);
    transpose_w<<<(768 * 512 + 255) / 256, 256, 0, stream>>>(W3, w3t, 512, 726, 768);
    transpose_w<<<(128 * 512 + 255) / 256, 256, 0, stream>>>(R3, r3t, 512, 121, 128);
    f32_to_bf16<<<(NN * 128 / 4 + 255) / 256, 256, 0, stream>>>(x0, x0b, NN * 128);

    // --- Layer 1: 128 -> 4x128 concat, res = x0 @ R1, elu ---
    gemm_mfma<<<dim3(4, MB), 256, 0, stream>>>(x0b, w1t, hbuf, NN, 128, 512, 512);
    gemm_mfma<<<dim3(4, MB), 256, 0, stream>>>(x0b, r1t, x1,   NN, 128, 512, 512);
    escore4<<<AB, 256, 0, stream>>>(hbuf, a1s, a1d, es, ed);
    pw_kernel<4><<<EB, 256, 0, stream>>>(es, ed, esrc, edst, pw, NE);   // pw overwrites x0b (dead)
    agg_w512<<<AB, 256, 0, stream>>>(hbuf, pw, rowp, esrc, x1, x1);

    // --- Layer 2: 512 -> 4x128 concat, res = identity(x1), elu (in place) ---
    gemm_mfma<<<dim3(4, MB), 256, 0, stream>>>(x1, w2t, hbuf, NN, 512, 512, 512);
    escore4<<<AB, 256, 0, stream>>>(hbuf, a2s, a2d, es, ed);
    pw_kernel<4><<<EB, 256, 0, stream>>>(es, ed, esrc, edst, pw, NE);
    agg_w512<<<AB, 256, 0, stream>>>(hbuf, pw, rowp, esrc, x1, x1);

    // --- Layer 3: 512 -> 6x121 avg, res = x1 @ R3 (fp32 -> d_out), identity ---
    gemm_mfma<<<dim3(6, MB), 256, 0, stream>>>(x1, w3t, hbuf, NN, 512, 728, 726);
    gemm_mfma<<<dim3(1, MB), 256, 0, stream>>>(x1, r3t, out,  NN, 512, 121, 121);
    escore6<<<AB, 256, 0, stream>>>(hbuf, a3s, a3d, es, ed);
    pw_kernel<6><<<EB, 256, 0, stream>>>(es, ed, esrc, edst, pw, NE);
    agg_w726<<<AB, 256, 0, stream>>>(hbuf, pw, rowp, esrc, out, out);
}